// Round 6
// baseline (149.599 us; speedup 1.0000x reference)
//
#include <hip/hip_runtime.h>
#include <hip/hip_bf16.h>
#include <math.h>

// ---------------- problem constants ----------------
#define NANC   5184        // 24*24*9
#define NPOS   576         // 24*24
#define CIN    512
#define MIDC   24
#define KANC   9
#define IMGW   384.0f
#define IMGM1  383.0f
#define MINSZ  16.0f
#define THRESH 0.7f

// d_out float offsets (outputs concatenated flat in return order)
#define OFF_PROP 0           // proposals  N*4
#define OFF_CLS  20736       // cls_out    N*2
#define OFF_FILT 31104       // filtered   N*4
#define OFF_PK   51840       // probs_kept N
#define OFF_LBL  57024       // labels_kept N (int -> float)
#define OFF_KEEP 62208       // keep       N (bool -> float)

// NMS capacity (geometric valid count is exactly 808)
#define MCAP 896
#define GCAP 14              // MCAP/64
#define TOTW (64 * (GCAP*(GCAP+1)/2))   // 6720 triangular u64 words

// ---------------- ws byte offsets ----------------
#define WS_BOX   1622016      // N float4   clipped boxes x0,y0,x1,y1
#define WS_PROB  1953792      // N f        softmax prob of class 1
#define WS_KEYS  2036736      // 1024 u64   sort keys of valid anchors
#define WS_SIDX  2044928      // 1024 i32   sorted orig indices
#define WS_SBOX  2049024      // MCAP float4 sorted boxes
#define WS_MASK  2063360      // TOTW u64   triangular IoU mask
#define WS_CNT   2117120      // u32        valid counter

// ============ K1: conv3x3+relu + heads + decode + score (fused, no prep) ============
// 144 blocks x 512 threads (ic = tid); each block = 4 consecutive positions in a row.
// x read directly (per-lane gather, L2-resident); W read with kk-innermost (L1 line reuse).
__global__ __launch_bounds__(512) void k_main(
        const float* __restrict__ x, const float* __restrict__ W,
        const float* __restrict__ brpn,
        const float* __restrict__ Wc, const float* __restrict__ bc,
        const float* __restrict__ Wr, const float* __restrict__ br,
        const float* __restrict__ anchors,
        float* __restrict__ out, float4* __restrict__ boxes,
        float* __restrict__ probs, unsigned long long* __restrict__ vkeys,
        unsigned* __restrict__ cnt) {
    const int tid = threadIdx.x;           // = input channel
    const int y = blockIdx.x / 6;
    const int xb = (blockIdx.x % 6) * 4;

    // x window for this block's 4 positions (+halo): rows y-1..y+1, cols xb-1..xb+4
    float xw[3][6];
    const float* xc = x + tid * NPOS;
    #pragma unroll
    for (int r = 0; r < 3; ++r) {
        int yy = y - 1 + r;
        #pragma unroll
        for (int c = 0; c < 6; ++c) {
            int xx = xb - 1 + c;
            bool in = (yy >= 0) & (yy < 24) & (xx >= 0) & (xx < 24);
            xw[r][c] = in ? xc[yy * 24 + xx] : 0.f;
        }
    }

    float acc[24][4];
    #pragma unroll
    for (int oc = 0; oc < 24; ++oc)
        #pragma unroll
        for (int p = 0; p < 4; ++p) acc[oc][p] = 0.f;

    const float* wp = W + tid * 9;         // W[(oc*512+ic)*9+kk]
    #pragma unroll
    for (int oc = 0; oc < 24; ++oc) {
        #pragma unroll
        for (int kk = 0; kk < 9; ++kk) {   // kk innermost in memory: L1 reuse
            const int r = kk / 3, c = kk % 3;
            float wv = wp[oc * (CIN * 9) + kk];
            #pragma unroll
            for (int p = 0; p < 4; ++p)
                acc[oc][p] += wv * xw[r][c + p];
        }
    }
    // butterfly reduce across the 64-lane wave
    #pragma unroll
    for (int oc = 0; oc < 24; ++oc)
        #pragma unroll
        for (int p = 0; p < 4; ++p) {
            float v = acc[oc][p];
            #pragma unroll
            for (int m = 1; m < 64; m <<= 1) v += __shfl_xor(v, m, 64);
            acc[oc][p] = v;
        }

    __shared__ float red[8][96];
    __shared__ float h_ld[4 * 24];
    __shared__ float cls_ld[4 * 18];
    __shared__ float reg_ld[4 * 36];
    const int wave = tid >> 6, lane = tid & 63;
    if (lane == 0) {
        #pragma unroll
        for (int oc = 0; oc < 24; ++oc)
            #pragma unroll
            for (int p = 0; p < 4; ++p) red[wave][oc * 4 + p] = acc[oc][p];
    }
    __syncthreads();
    if (tid < 96) {
        float s = 0.f;
        #pragma unroll
        for (int w = 0; w < 8; ++w) s += red[w][tid];
        int oc = tid >> 2, p = tid & 3;
        h_ld[p * 24 + oc] = fmaxf(s + brpn[oc], 0.f);
    }
    __syncthreads();
    if (tid < 216) {    // 4 pos * 54 outputs (18 cls + 36 reg)
        int p = tid / 54, o = tid % 54;
        const float* hv = h_ld + p * 24;
        if (o < 18) {
            float s = bc[o];
            const float* w = Wc + o * 24;
            #pragma unroll
            for (int c = 0; c < 24; ++c) s += w[c] * hv[c];
            cls_ld[p * 18 + o] = s;
            out[OFF_CLS + (y * 24 + xb + p) * 18 + o] = s;
        } else {
            int o2 = o - 18;
            float s = br[o2];
            const float* w = Wr + o2 * 24;
            #pragma unroll
            for (int c = 0; c < 24; ++c) s += w[c] * hv[c];
            reg_ld[p * 36 + o2] = s;
        }
    }
    __syncthreads();
    if (tid < 36) {     // 4 pos * 9 anchors
        #pragma clang fp contract(off)
        int p = tid / 9, k = tid % 9;
        int n = (y * 24 + xb + p) * 9 + k;
        float ax = anchors[4 * n], ay = anchors[4 * n + 1];
        float aw = anchors[4 * n + 2], ah = anchors[4 * n + 3];
        float tx = reg_ld[p * 36 + 4 * k],     ty = reg_ld[p * 36 + 4 * k + 1];
        float tw = reg_ld[p * 36 + 4 * k + 2], th = reg_ld[p * 36 + 4 * k + 3];
        float px = ax + aw * tx, py = ay + ah * ty;
        float pw = aw * expf(tw), ph = ah * expf(th);
        out[OFF_PROP + 4 * n]     = px;
        out[OFF_PROP + 4 * n + 1] = py;
        out[OFF_PROP + 4 * n + 2] = pw;
        out[OFF_PROP + 4 * n + 3] = ph;
        // geometric validity straight from anchors (exact in f32)
        float gx0 = ax - 0.5f * (aw - 1.f);
        float gy0 = ay - 0.5f * (ah - 1.f);
        float gx1 = aw + gx0 - 1.f;
        float gy1 = ah + gy0 - 1.f;
        bool geo_ok = (gx0 >= 0.f) & (gy0 >= 0.f) & (gx1 < IMGW) & (gy1 < IMGW);
        float x0 = px - 0.5f * (pw - 1.f);
        float y0 = py - 0.5f * (ph - 1.f);
        float x1 = pw + x0 - 1.f;
        float y1 = ph + y0 - 1.f;
        x0 = fminf(fmaxf(x0, 0.f), IMGM1);
        x1 = fminf(fmaxf(x1, 0.f), IMGM1);
        y0 = fminf(fmaxf(y0, 0.f), IMGM1);
        y1 = fminf(fmaxf(y1, 0.f), IMGM1);
        float wsb = x1 - x0 + 1.f, hsb = y1 - y0 + 1.f;
        float c0 = cls_ld[p * 18 + 2 * k], c1 = cls_ld[p * 18 + 2 * k + 1];
        float mx = fmaxf(c0, c1);
        float e0 = expf(c0 - mx), e1 = expf(c1 - mx);
        float pr = e1 / (e0 + e1);
        boxes[n] = make_float4(x0, y0, x1, y1);
        probs[n] = pr;
        bool valid = geo_ok && (wsb >= MINSZ) && (hsb >= MINSZ);
        if (valid) {
            unsigned pos = atomicAdd(cnt, 1u);
            unsigned u = __float_as_uint(pr);
            unsigned enc = u ^ ((u >> 31) ? 0xFFFFFFFFu : 0x80000000u); // ascending in value
            vkeys[pos] = ((unsigned long long)(~enc) << 32) | (unsigned)n; // asc sort => desc prob, tie: idx asc
        }
    }
}

// ============ K2: rank-by-count ordering (keys unique => exact stable sort) ============
__global__ __launch_bounds__(64) void k_rank(const unsigned long long* __restrict__ vkeys,
                                             const unsigned* __restrict__ cnt,
                                             int* __restrict__ sidx,
                                             float4* __restrict__ sbox,
                                             const float4* __restrict__ boxes) {
    __shared__ unsigned long long keys[MCAP];
    const int t = threadIdx.x;
    unsigned Mc = *cnt; int M = (int)(Mc < (unsigned)MCAP ? Mc : (unsigned)MCAP);
    for (int i = t; i < M; i += 64) keys[i] = vkeys[i];
    __syncthreads();
    int i = blockIdx.x * 64 + t;
    if (i < M) {
        unsigned long long ki = keys[i];
        int r = 0;
        #pragma unroll 4
        for (int j = 0; j < M; ++j) r += (keys[j] < ki) ? 1 : 0;
        int n = (int)(ki & 0xFFFFFFFFu);
        sidx[r] = n;
        sbox[r] = boxes[n];
    }
}

// ============ K3: triangular IoU>thresh bitmask ============
__global__ __launch_bounds__(256) void k_mask(const float4* __restrict__ sbox,
                                              const unsigned* __restrict__ cnt,
                                              unsigned long long* __restrict__ mask) {
    __shared__ float4 sb[MCAP];
    const int t = threadIdx.x;
    for (int i = t; i < MCAP; i += 256) sb[i] = sbox[i];
    __syncthreads();
    unsigned Mc = *cnt; unsigned M = Mc < (unsigned)MCAP ? Mc : (unsigned)MCAP;
    int widx = blockIdx.x * 256 + t;
    if (widx >= TOTW) return;
    // decode triangular word index -> (row i, column group gw)
    int g = 0, base = 0;
    while (g < GCAP - 1) {
        int nb = base + 64 * (GCAP - g);
        if (widx < nb) break;
        base = nb; ++g;
    }
    int rem = widx - base;
    int r = rem / (GCAP - g);
    int gw = g + rem % (GCAP - g);
    int i = g * 64 + r;
    if (i >= (int)M) return;       // row never read
    {
        #pragma clang fp contract(off)
        float4 bi = sb[i];
        float ai = (bi.z - bi.x + 1.f) * (bi.w - bi.y + 1.f);
        unsigned long long w = 0;
        #pragma unroll 4
        for (int b = 0; b < 64; ++b) {
            int j = gw * 64 + b;
            if (j > i) {
                float4 bj = sb[j];
                float iw = fminf(bi.z, bj.z) - fmaxf(bi.x, bj.x) + 1.f;
                float ih = fminf(bi.w, bj.w) - fmaxf(bi.y, bj.y) + 1.f;
                iw = fmaxf(iw, 0.f); ih = fmaxf(ih, 0.f);
                float inter = iw * ih;
                float aj = (bj.z - bj.x + 1.f) * (bj.w - bj.y + 1.f);
                float iou = inter / (ai + aj - inter);
                if (iou > THRESH) w |= 1ULL << b;
            }
        }
        mask[widx] = w;
    }
}

// ============ K4: greedy NMS (nz-shortcut serial + parallel cross-group) ============
__global__ __launch_bounds__(1024) void k_nms(const unsigned long long* __restrict__ mask_g,
                                              const int* __restrict__ sidx_g,
                                              const unsigned* __restrict__ cnt,
                                              const float4* __restrict__ boxes,
                                              const float* __restrict__ probs,
                                              const int* __restrict__ labels,
                                              float* __restrict__ out) {
    __shared__ unsigned long long mk[TOTW];          // 52.5 KB
    __shared__ int sidx[MCAP];
    __shared__ unsigned long long keepm[81];         // keep bits in ORIGINAL index space
    __shared__ unsigned long long keeps[GCAP];       // keep bits in SORTED space
    __shared__ unsigned long long suppw[GCAP];       // running suppression words
    const int t = threadIdx.x;
    unsigned Mc = *cnt; unsigned M = Mc < (unsigned)MCAP ? Mc : (unsigned)MCAP;
    for (int i = t; i < TOTW; i += 1024) mk[i] = mask_g[i];
    if (t < MCAP) sidx[t] = sidx_g[t];
    if (t < 81) keepm[t] = 0;
    if (t < GCAP) { keeps[t] = 0; suppw[t] = 0; }
    __syncthreads();
    const int wid = t >> 6, lane = t & 63;
    const int ngroups = (int)((M + 63) >> 6);
    for (int g = 0; g < ngroups; ++g) {
        const int rowstride = GCAP - g;
        const int base_g = 64 * (GCAP * g - (g * (g - 1)) / 2);
        int nbits = (int)M - g * 64; if (nbits > 64) nbits = 64;
        unsigned long long vmaskbits = (nbits < 64) ? ((1ULL << nbits) - 1ULL) : ~0ULL;
        if (wid == 0) {
            // lane r holds the in-group (diagonal) word of row (g,r)
            unsigned long long diag = mk[base_g + lane * rowstride];
            unsigned dlo = (unsigned)diag, dhi = (unsigned)(diag >> 32);
            unsigned long long supp = suppw[g];
            unsigned long long nz = __ballot(diag != 0ULL) & vmaskbits;
            while (nz) {
                int r = __ffsll(nz) - 1;
                nz &= nz - 1;
                if (!((supp >> r) & 1ULL)) {
                    unsigned rlo = (unsigned)__builtin_amdgcn_readlane((int)dlo, r);
                    unsigned rhi = (unsigned)__builtin_amdgcn_readlane((int)dhi, r);
                    supp |= ((unsigned long long)rhi << 32) | rlo;
                }
            }
            if (lane == 0) keeps[g] = ~supp & vmaskbits;
        }
        __syncthreads();
        // parallel cross-group suppression: wave h==wid updates word h (g<h<GCAP)
        if (wid > g && wid < GCAP) {
            unsigned long long kw = keeps[g];
            unsigned long long v = ((kw >> lane) & 1ULL)
                ? mk[base_g + lane * rowstride + (wid - g)] : 0ULL;
            unsigned vlo = (unsigned)v, vhi = (unsigned)(v >> 32);
            #pragma unroll
            for (int m = 1; m < 64; m <<= 1) {
                vlo |= __shfl_xor(vlo, m, 64);
                vhi |= __shfl_xor(vhi, m, 64);
            }
            if (lane == 0)
                suppw[wid] |= ((unsigned long long)vhi << 32) | vlo;
        }
        __syncthreads();
    }
    if (t < (int)M) {
        if ((keeps[t >> 6] >> (t & 63)) & 1ULL) {
            int n = sidx[t];
            atomicOr(&keepm[n >> 6], 1ULL << (n & 63));
        }
    }
    __syncthreads();
    for (int n = t; n < NANC; n += 1024) {
        unsigned long long kb = (keepm[n >> 6] >> (n & 63)) & 1ULL;
        float kf = kb ? 1.f : 0.f;
        float4 b = boxes[n];
        float wsb = b.z - b.x + 1.f, hsb = b.w - b.y + 1.f;
        float4 fo;
        fo.x = (b.x + 0.5f * (wsb - 1.f)) * kf;
        fo.y = (b.y + 0.5f * (hsb - 1.f)) * kf;
        fo.z = wsb * kf;
        fo.w = hsb * kf;
        *reinterpret_cast<float4*>(out + OFF_FILT + 4 * n) = fo;
        out[OFF_PK + n]  = probs[n] * kf;
        out[OFF_LBL + n] = kb ? (float)labels[n] : 0.f;
        out[OFF_KEEP + n] = kf;
    }
}

extern "C" void kernel_launch(void* const* d_in, const int* in_sizes, int n_in,
                              void* d_out, int out_size, void* d_ws, size_t ws_size,
                              hipStream_t stream) {
    const float* x        = (const float*)d_in[0];
    const int*   labels   = (const int*)d_in[1];
    const float* Wrpn     = (const float*)d_in[2];
    const float* brpn     = (const float*)d_in[3];
    const float* Wcls     = (const float*)d_in[4];
    const float* bcls     = (const float*)d_in[5];
    const float* Wreg     = (const float*)d_in[6];
    const float* breg     = (const float*)d_in[7];
    const float* anchors  = (const float*)d_in[8];
    float* out = (float*)d_out;
    char* ws = (char*)d_ws;

    float4* boxes = (float4*)(ws + WS_BOX);
    float*  probs = (float*)(ws + WS_PROB);
    unsigned long long* vkeys = (unsigned long long*)(ws + WS_KEYS);
    int*    sidx  = (int*)(ws + WS_SIDX);
    float4* sbox  = (float4*)(ws + WS_SBOX);
    unsigned long long* mask = (unsigned long long*)(ws + WS_MASK);
    unsigned* cnt = (unsigned*)(ws + WS_CNT);

    hipMemsetAsync(cnt, 0, 4, stream);
    k_main<<<144, 512, 0, stream>>>(x, Wrpn, brpn, Wcls, bcls, Wreg, breg,
                                    anchors, out, boxes, probs, vkeys, cnt);
    k_rank<<<GCAP, 64, 0, stream>>>(vkeys, cnt, sidx, sbox, boxes);
    k_mask<<<27, 256, 0, stream>>>(sbox, cnt, mask);
    k_nms<<<1, 1024, 0, stream>>>(mask, sidx, cnt, boxes, probs, labels, out);
}